// Round 13
// baseline (236.637 us; speedup 1.0000x reference)
//
#include <hip/hip_runtime.h>
#include <math.h>

#define LOG2E_F 1.4426950408889634f
#define LN2_F   0.6931471805599453f

constexpr int Bn = 1024;
constexpr int Tn = 512;
constexpr int Ln = 32;

typedef unsigned int uint2v __attribute__((ext_vector_type(2)));

// ---- cross-lane swaps (runtime-probed mapping, VALU permlane ops) ----------
#if __has_builtin(__builtin_amdgcn_permlane32_swap)
#define PROBE32 \
    bool use_y32; \
    { \
        const uint2v r = __builtin_amdgcn_permlane32_swap((unsigned)l, (unsigned)l, false, false); \
        const bool selA = __all((((l < 32) ? (int)r[1] : (int)r[0]) == (l ^ 32)) ? 1 : 0); \
        use_y32 = selA ? (l < 32) : (l >= 32); \
    }
#define CROSS32(p, out) { \
    const uint2v r_ = __builtin_amdgcn_permlane32_swap( \
        __float_as_uint(p), __float_as_uint(p), false, false); \
    out = __uint_as_float(use_y32 ? r_[1] : r_[0]); }
#else
#define PROBE32
#define CROSS32(p, out) out = __shfl_xor((p), 32);
#endif

#if __has_builtin(__builtin_amdgcn_permlane16_swap)
#define PROBE16 \
    bool use_r016; \
    { \
        const uint2v r = __builtin_amdgcn_permlane16_swap((unsigned)l, (unsigned)l, false, false); \
        const bool selA = __all(((((l & 16) ? (int)r[0] : (int)r[1])) == (l ^ 16)) ? 1 : 0); \
        use_r016 = selA ? ((l & 16) != 0) : ((l & 16) == 0); \
    }
#define CROSS16(p, out) { \
    const uint2v r_ = __builtin_amdgcn_permlane16_swap( \
        __float_as_uint(p), __float_as_uint(p), false, false); \
    out = __uint_as_float(use_r016 ? r_[0] : r_[1]); }
#else
#define PROBE16
#define CROSS16(p, out) out = __int_as_float(__builtin_amdgcn_ds_swizzle( \
        __float_as_int(p), 0x401F));
#endif

// ---- emission load machinery (asm, group-banked, vmcnt(0) drain) -----------
#define ISS1(REG, TT, COL) {                                                \
    int ts_ = (TT);                                                         \
    ts_ = ts_ < 0 ? 0 : (ts_ > (Tn - 1) ? (Tn - 1) : ts_);                  \
    const unsigned voff_ = (unsigned)ts_ * (unsigned)(Ln * 4) + (COL);      \
    asm volatile("global_load_dword %0, %1, %2"                             \
                 : "=v"(REG) : "v"(voff_), "s"(xb)); }

#define ISSUE16(P, TB)                                                      \
    ISS1(P##0,  (TB),            col4O) ISS1(P##1,  (TB) + 1  * dtt, col4E) \
    ISS1(P##2,  (TB) + 2 * dtt,  col4O) ISS1(P##3,  (TB) + 3  * dtt, col4E) \
    ISS1(P##4,  (TB) + 4 * dtt,  col4O) ISS1(P##5,  (TB) + 5  * dtt, col4E) \
    ISS1(P##6,  (TB) + 6 * dtt,  col4O) ISS1(P##7,  (TB) + 7  * dtt, col4E) \
    ISS1(P##8,  (TB) + 8 * dtt,  col4O) ISS1(P##9,  (TB) + 9  * dtt, col4E) \
    ISS1(P##10, (TB) + 10 * dtt, col4O) ISS1(P##11, (TB) + 11 * dtt, col4E) \
    ISS1(P##12, (TB) + 12 * dtt, col4O) ISS1(P##13, (TB) + 13 * dtt, col4E) \
    ISS1(P##14, (TB) + 14 * dtt, col4O) ISS1(P##15, (TB) + 15 * dtt, col4E)

#define WAITALL(P)                                                          \
    asm volatile("s_waitcnt vmcnt(0)"                                       \
        : "+v"(P##0), "+v"(P##1), "+v"(P##2),  "+v"(P##3),                  \
          "+v"(P##4), "+v"(P##5), "+v"(P##6),  "+v"(P##7),                  \
          "+v"(P##8), "+v"(P##9), "+v"(P##10), "+v"(P##11),                 \
          "+v"(P##12), "+v"(P##13), "+v"(P##14), "+v"(P##15)                \
        : : "memory");

#define COPY16(D, S)                                                        \
    D##0 = S##0;   D##1 = S##1;   D##2 = S##2;   D##3 = S##3;               \
    D##4 = S##4;   D##5 = S##5;   D##6 = S##6;   D##7 = S##7;               \
    D##8 = S##8;   D##9 = S##9;   D##10 = S##10; D##11 = S##11;             \
    D##12 = S##12; D##13 = S##13; D##14 = S##14; D##15 = S##15;

// ---- step core: alternating layout, ONE cross per step ---------------------
// Odd steps (from phi-layout):  table EiA, combine CROSS16 -> sigma-layout.
// Even steps (from sigma):      table EiB, combine CROSS32 -> phi-layout.
#define ROT(T) __int_as_float(__builtin_amdgcn_update_dpp(                  \
        0, __float_as_int(xs), 0x120 + (T), 0xF, 0xF, true))

#define STEP_BODY(ET, CRX, PRE, NXTV)                                       \
    const float gcur = ggc;                                                 \
    if (PRE) ggc = __builtin_amdgcn_exp2f((NXTV) * LOG2E_F);                \
    const float xs = dir ? x * gcur : x;   /* bw: emission at writer */     \
    const float r1  = ROT(1);   const float r2  = ROT(2);                   \
    const float r3  = ROT(3);   const float r4  = ROT(4);                   \
    const float r5  = ROT(5);   const float r6  = ROT(6);                   \
    const float r7  = ROT(7);   const float r8  = ROT(8);                   \
    const float r9  = ROT(9);   const float r10 = ROT(10);                  \
    const float r11 = ROT(11);  const float r12 = ROT(12);                  \
    const float r13 = ROT(13);  const float r14 = ROT(14);                  \
    const float r15 = ROT(15);                                              \
    float a0 = xs * ET[0];   float a1 = r1 * ET[1];                         \
    float a2 = r2 * ET[2];   float a3 = r3 * ET[3];                         \
    a0 = fmaf(r4,  ET[4],  a0);   a1 = fmaf(r5,  ET[5],  a1);               \
    a2 = fmaf(r6,  ET[6],  a2);   a3 = fmaf(r7,  ET[7],  a3);               \
    a0 = fmaf(r8,  ET[8],  a0);   a1 = fmaf(r9,  ET[9],  a1);               \
    a2 = fmaf(r10, ET[10], a2);   a3 = fmaf(r11, ET[11], a3);               \
    a0 = fmaf(r12, ET[12], a0);   a1 = fmaf(r13, ET[13], a1);               \
    a2 = fmaf(r14, ET[14], a2);   a3 = fmaf(r15, ET[15], a3);               \
    const float partial = (a0 + a1) + (a2 + a3);                            \
    float cross; CRX(partial, cross)                                        \
    float full = partial + cross;                                           \
    if (dir == 0) full *= gcur;            /* fw: emission at reader */

#define RENORM {                                                            \
    const int cb = __builtin_amdgcn_readfirstlane(                          \
        __float_as_int(fmaxf(capv, 1e-30f)));                               \
    const int ee = ((cb >> 23) & 255) - 127;                                \
    x *= __int_as_float((127 - ee) << 23);                                  \
    Mr += (float)ee; }

#define STEPF(ET, CRX, PRE, NXTV, CAP, RN) {                                \
    STEP_BODY(ET, CRX, PRE, NXTV)                                           \
    x = full;                                                               \
    if (CAP) capv = x;                                                      \
    if (RN) RENORM }

#define STEPT(R, ET, CRX, PRE, NXTV, CAP, RN) {                             \
    STEP_BODY(ET, CRX, PRE, NXTV)                                           \
    const bool act = ((kb + (R)) <= K);                                     \
    x = act ? full : x;                                                     \
    if (CAP) capv = x;                                                      \
    if (RN) RENORM }

#define STEPS16F(P)                                                         \
    ggc = __builtin_amdgcn_exp2f(P##0 * LOG2E_F);                           \
    STEPF(EiA, CROSS16, 1, P##1,  0, 0)                                     \
    STEPF(EiB, CROSS32, 1, P##2,  0, 0)                                     \
    STEPF(EiA, CROSS16, 1, P##3,  1, 0)                                     \
    STEPF(EiB, CROSS32, 1, P##4,  0, 1)                                     \
    STEPF(EiA, CROSS16, 1, P##5,  0, 0)                                     \
    STEPF(EiB, CROSS32, 1, P##6,  0, 0)                                     \
    STEPF(EiA, CROSS16, 1, P##7,  1, 0)                                     \
    STEPF(EiB, CROSS32, 1, P##8,  0, 1)                                     \
    STEPF(EiA, CROSS16, 1, P##9,  0, 0)                                     \
    STEPF(EiB, CROSS32, 1, P##10, 0, 0)                                     \
    STEPF(EiA, CROSS16, 1, P##11, 1, 0)                                     \
    STEPF(EiB, CROSS32, 1, P##12, 0, 1)                                     \
    STEPF(EiA, CROSS16, 1, P##13, 0, 0)                                     \
    STEPF(EiB, CROSS32, 1, P##14, 0, 0)                                     \
    STEPF(EiA, CROSS16, 1, P##15, 1, 0)                                     \
    STEPF(EiB, CROSS32, 0, P##15, 0, 1)                                     \
    kb += 16;

#define STEPS16T(P)                                                         \
    ggc = __builtin_amdgcn_exp2f(P##0 * LOG2E_F);                           \
    STEPT(0,  EiA, CROSS16, 1, P##1,  0, 0)                                 \
    STEPT(1,  EiB, CROSS32, 1, P##2,  0, 0)                                 \
    STEPT(2,  EiA, CROSS16, 1, P##3,  1, 0)                                 \
    STEPT(3,  EiB, CROSS32, 1, P##4,  0, 1)                                 \
    STEPT(4,  EiA, CROSS16, 1, P##5,  0, 0)                                 \
    STEPT(5,  EiB, CROSS32, 1, P##6,  0, 0)                                 \
    STEPT(6,  EiA, CROSS16, 1, P##7,  1, 0)                                 \
    STEPT(7,  EiB, CROSS32, 1, P##8,  0, 1)                                 \
    STEPT(8,  EiA, CROSS16, 1, P##9,  0, 0)                                 \
    STEPT(9,  EiB, CROSS32, 1, P##10, 0, 0)                                 \
    STEPT(10, EiA, CROSS16, 1, P##11, 1, 0)                                 \
    STEPT(11, EiB, CROSS32, 1, P##12, 0, 1)                                 \
    STEPT(12, EiA, CROSS16, 1, P##13, 0, 0)                                 \
    STEPT(13, EiB, CROSS32, 1, P##14, 0, 0)                                 \
    STEPT(14, EiA, CROSS16, 1, P##15, 1, 0)                                 \
    STEPT(15, EiB, CROSS32, 0, P##15, 0, 1)                                 \
    kb += 16;

// Both E tables (EA: odd/phi-layout steps, EB: even/sigma-layout steps).
#define EI_SETUP2                                                           \
    float EiA[16], EiB[16];                                                 \
    {                                                                       \
        float tmax = -3.4e38f;                                              \
        _Pragma("unroll")                                                   \
        for (int t = 0; t < 16; ++t) {                                      \
            const int sg = ror_minus ? ((k15 - t) & 15) : ((k15 + t) & 15); \
            const int iA = 16 * ihA + sg;                                   \
            const int iB = 16 * ihB + sg;                                   \
            const float tvA = dir ? trans[labA * Ln + iA]                   \
                                  : trans[iA * Ln + labA];                  \
            const float tvB = dir ? trans[labB * Ln + iB]                   \
                                  : trans[iB * Ln + labB];                  \
            EiA[t] = tvA;  EiB[t] = tvB;                                    \
            tmax = fmaxf(tmax, tvA);    /* EA spans all of trans */         \
        }                                                                   \
        _Pragma("unroll")                                                   \
        for (int off = 1; off < 64; off <<= 1)                              \
            tmax = fmaxf(tmax, __shfl_xor(tmax, off));                      \
        tmax2 = tmax * LOG2E_F;                                             \
        _Pragma("unroll")                                                   \
        for (int t = 0; t < 16; ++t) {                                      \
            EiA[t] = __builtin_amdgcn_exp2f((EiA[t] - tmax) * LOG2E_F);     \
            EiB[t] = __builtin_amdgcn_exp2f((EiB[t] - tmax) * LOG2E_F);     \
        }                                                                   \
    }

// ---- real chain kernel ------------------------------------------------------
__global__ __launch_bounds__(64)
void crf_chain_kernel(const float* __restrict__ logits,
                      const float* __restrict__ trans,
                      const int* __restrict__ seq_lens,
                      float* __restrict__ ws)
{
    const int blk = blockIdx.x;
    const int b   = blk >> 1;
    const int dir = blk & 1;
    const int l   = threadIdx.x;
    const int k15 = l & 15;
    const int labB = l & 31;                        // phi label
    const int labA = (l & 15) | ((l >> 5) << 4);    // sigma label
    const int ihA  = (l >> 4) & 1;                  // row-half, phi-layout
    const int ihB  = (l >> 5) & 1;                  // row-half, sigma-layout

    int len = seq_lens[b];
    len = len < 1 ? 1 : (len > Tn ? Tn : len);
    const int m  = (len + 1) >> 1;
    const int K  = dir ? (len - m) : (m - 1);
    const int nfull = K >> 4;
    const int ktail = K & 15;

    const float* xb = logits + (size_t)b * (Tn * Ln);

    const int w0 = __builtin_amdgcn_readfirstlane(
        __builtin_amdgcn_update_dpp(0, l, 0x121, 0xF, 0xF, true));
    const bool ror_minus = (w0 == 15);
    PROBE32
    PROBE16

    float tmax2;
    EI_SETUP2

    // init state in phi-layout
    float x, Minit;
    if (dir == 0) {
        const float a0v = xb[labB] * LOG2E_F;
        float mx = a0v;
        #pragma unroll
        for (int off = 1; off < 64; off <<= 1)
            mx = fmaxf(mx, __shfl_xor(mx, off));
        x = __builtin_amdgcn_exp2f(a0v - mx);
        Minit = mx;
    } else {
        x = 1.0f;
        Minit = 0.0f;
    }
    float Mr = 0.0f;
    float capv = x;

    // emission columns per step parity (odd k: fw->labA, bw->labB; even swaps)
    const unsigned col4O = (unsigned)(dir ? labB : labA) * 4u;
    const unsigned col4E = (unsigned)(dir ? labA : labB) * 4u;
    const int dtt = dir ? -1 : 1;
    const int t0  = dir ? (len - 1) : 1;

    float A0, A1, A2, A3, A4, A5, A6, A7;
    float A8, A9, A10, A11, A12, A13, A14, A15;
    float B0, B1, B2, B3, B4, B5, B6, B7;
    float B8, B9, B10, B11, B12, B13, B14, B15;

    float ggc = 1.0f;
    int kb = 1;

    ISSUE16(B, t0)
    WAITALL(B)
    COPY16(A, B)
    int tnext = t0 + 16 * dtt;

    for (int g = 0; g < nfull; ++g) {
        ISSUE16(B, tnext)
        tnext += 16 * dtt;
        __builtin_amdgcn_sched_barrier(0);
        STEPS16F(A)
        __builtin_amdgcn_sched_barrier(0);
        WAITALL(B)
        __builtin_amdgcn_sched_barrier(0);
        COPY16(A, B)
    }
    if (ktail) {
        STEPS16T(A)
    }

    asm volatile("s_waitcnt vmcnt(0)" ::: "memory");

    const float M = Minit + (float)K * tmax2 + Mr;

    // final layout depends on parity of K: even -> phi, odd -> sigma
    float* wsrow = ws + (size_t)(b * 2 + dir) * 33;
    if (K & 1) {
        if ((l & 16) == 0) wsrow[labA] = x;
    } else {
        if (l < 32) wsrow[l] = x;
    }
    if (l == 0) wsrow[32] = M;
}

// ---- probe V2': full alternating step, loads removed, uniform steps --------
template<int NSTEP>
__global__ __launch_bounds__(64)
void crf_probe_step(const float* __restrict__ logits,
                    const float* __restrict__ trans,
                    float* __restrict__ ws)
{
    const int blk = blockIdx.x;
    const int b   = blk >> 1;
    const int dir = blk & 1;
    const int l   = threadIdx.x;
    const int k15 = l & 15;
    const int labB = l & 31;
    const int labA = (l & 15) | ((l >> 5) << 4);
    const int ihA  = (l >> 4) & 1;
    const int ihB  = (l >> 5) & 1;

    const float* xb = logits + (size_t)b * (Tn * Ln);
    (void)xb;

    const int w0 = __builtin_amdgcn_readfirstlane(
        __builtin_amdgcn_update_dpp(0, l, 0x121, 0xF, 0xF, true));
    const bool ror_minus = (w0 == 15);
    PROBE32
    PROBE16

    float tmax2;
    EI_SETUP2
    (void)tmax2;

    float x = 1.0f + (float)labB * 0.015625f;
    float Mr = 0.0f;
    float capv = x;
    const int K = NSTEP + 1;
    int kb = 1;
    (void)K;
    float ggc = 1.0f;

    float F0  = 1.00f + (float)((labB * 7 + 0)  & 31) * 0.01f;
    float F1  = 1.00f + (float)((labB * 7 + 3)  & 31) * 0.01f;
    float F2  = 1.00f + (float)((labB * 7 + 6)  & 31) * 0.01f;
    float F3  = 1.00f + (float)((labB * 7 + 9)  & 31) * 0.01f;
    float F4  = 1.00f + (float)((labB * 7 + 12) & 31) * 0.01f;
    float F5  = 1.00f + (float)((labB * 7 + 15) & 31) * 0.01f;
    float F6  = 1.00f + (float)((labB * 7 + 18) & 31) * 0.01f;
    float F7  = 1.00f + (float)((labB * 7 + 21) & 31) * 0.01f;
    float F8  = 1.00f + (float)((labB * 7 + 24) & 31) * 0.01f;
    float F9  = 1.00f + (float)((labB * 7 + 27) & 31) * 0.01f;
    float F10 = 1.00f + (float)((labB * 7 + 30) & 31) * 0.01f;
    float F11 = 1.00f + (float)((labB * 7 + 1)  & 31) * 0.01f;
    float F12 = 1.00f + (float)((labB * 7 + 4)  & 31) * 0.01f;
    float F13 = 1.00f + (float)((labB * 7 + 7)  & 31) * 0.01f;
    float F14 = 1.00f + (float)((labB * 7 + 10) & 31) * 0.01f;
    float F15 = 1.00f + (float)((labB * 7 + 13) & 31) * 0.01f;

    for (int g = 0; g < NSTEP / 16; ++g) {
        STEPS16F(F)
    }

    if (l == 0) ws[(size_t)blk * 33] = x + Mr * 1e-30f;
}

// ---- probe V4': single-cross dependent chain (alternating 16/32) -----------
template<int NITER>
__global__ __launch_bounds__(64)
void crf_probe_cross(float* __restrict__ ws)
{
    const int l = threadIdx.x;
    PROBE32
    PROBE16

    float x = 1.0f + (float)(l & 31) * 0.015625f;
    for (int g = 0; g < NITER / 16; ++g) {
        #pragma unroll
        for (int r = 0; r < 16; ++r) {
            float c;
            if (r & 1) { CROSS32(x, c) } else { CROSS16(x, c) }
            const float s = x + c;
            x = __int_as_float((__float_as_int(s) & 0x007fffff) | 0x3f800000);
        }
    }
    if (l == 0) ws[(size_t)blockIdx.x * 33] = x;
}

// ---- combine kernel (unchanged) --------------------------------------------
__global__ __launch_bounds__(64)
void crf_combine_kernel(const float* __restrict__ logits,
                        const float* __restrict__ trans,
                        const int* __restrict__ labels,
                        const int* __restrict__ seq_lens,
                        const float* __restrict__ ws,
                        float* __restrict__ out)
{
    const int b    = blockIdx.x;
    const int lane = threadIdx.x;
    const int j    = lane & 31;

    int len = seq_lens[b];
    len = len < 1 ? 1 : (len > Tn ? Tn : len);

    const int*   lb = labels + (size_t)b * Tn;
    const float* xb = logits + (size_t)b * (Tn * Ln);

    float acc = 0.f;
    for (int t = lane; t < len; t += 64) {
        const int lt = lb[t];
        acc += xb[t * Ln + lt];
        if (t >= 1) acc += trans[lb[t - 1] * Ln + lt];
    }
    #pragma unroll
    for (int off = 1; off < 64; off <<= 1)
        acc += __shfl_xor(acc, off);

    const float* wf = ws + (size_t)(b * 2 + 0) * 33;
    const float* wb = ws + (size_t)(b * 2 + 1) * 33;
    float term = wf[j] * wb[j];
    #pragma unroll
    for (int off = 1; off < 32; off <<= 1)
        term += __shfl_xor(term, off);
    if (lane == 0) {
        const float Mf = wf[32], Mb = wb[32];
        out[b] = acc - (Mf + Mb + __builtin_amdgcn_logf(term)) * LN2_F;
    }
}

extern "C" void kernel_launch(void* const* d_in, const int* in_sizes, int n_in,
                              void* d_out, int out_size, void* d_ws, size_t ws_size,
                              hipStream_t stream) {
    const float* logits   = (const float*)d_in[0];
    const float* trans    = (const float*)d_in[1];
    const int*   labels   = (const int*)d_in[2];
    const int*   seq_lens = (const int*)d_in[3];
    float* out = (float*)d_out;
    float* ws  = (float*)d_ws;    // 2048 * 33 floats = 270 KB

    // probes (ws fully overwritten by the chain kernel afterwards):
    crf_probe_step<768><<<Bn * 2, 64, 0, stream>>>(logits, trans, ws);
    crf_probe_cross<1024><<<Bn * 2, 64, 0, stream>>>(ws);
    crf_probe_cross<1024><<<Bn * 2, 64, 0, stream>>>(ws);
    crf_probe_cross<1024><<<Bn * 2, 64, 0, stream>>>(ws);

    crf_chain_kernel<<<Bn * 2, 64, 0, stream>>>(logits, trans, seq_lens, ws);
    crf_combine_kernel<<<Bn, 64, 0, stream>>>(logits, trans, labels, seq_lens, ws, out);
}

// Round 16
// 48.437 us; speedup vs baseline: 4.8854x; 4.8854x over previous
//
#include <hip/hip_runtime.h>
#include <math.h>

#define LOG2E_F 1.4426950408889634f
#define LN2_F   0.6931471805599453f

constexpr int Bn = 1024;
constexpr int Tn = 512;
constexpr int Ln = 32;

typedef unsigned int uint2v __attribute__((ext_vector_type(2)));

// ---- cross-lane swaps (runtime-probed mapping, VALU permlane ops) ----------
#if __has_builtin(__builtin_amdgcn_permlane32_swap)
#define PROBE32 \
    bool use_y32; \
    { \
        const uint2v r = __builtin_amdgcn_permlane32_swap((unsigned)l, (unsigned)l, false, false); \
        const bool selA = __all((((l < 32) ? (int)r[1] : (int)r[0]) == (l ^ 32)) ? 1 : 0); \
        use_y32 = selA ? (l < 32) : (l >= 32); \
    }
#define CROSS32(p, out) { \
    const uint2v r_ = __builtin_amdgcn_permlane32_swap( \
        __float_as_uint(p), __float_as_uint(p), false, false); \
    out = __uint_as_float(use_y32 ? r_[1] : r_[0]); }
#else
#define PROBE32
#define CROSS32(p, out) out = __shfl_xor((p), 32);
#endif

#if __has_builtin(__builtin_amdgcn_permlane16_swap)
#define PROBE16 \
    bool use_r016; \
    { \
        const uint2v r = __builtin_amdgcn_permlane16_swap((unsigned)l, (unsigned)l, false, false); \
        const bool selA = __all(((((l & 16) ? (int)r[0] : (int)r[1])) == (l ^ 16)) ? 1 : 0); \
        use_r016 = selA ? ((l & 16) != 0) : ((l & 16) == 0); \
    }
#define CROSS16(p, out) { \
    const uint2v r_ = __builtin_amdgcn_permlane16_swap( \
        __float_as_uint(p), __float_as_uint(p), false, false); \
    out = __uint_as_float(use_r016 ? r_[0] : r_[1]); }
#else
#define PROBE16
#define CROSS16(p, out) out = __int_as_float(__builtin_amdgcn_ds_swizzle( \
        __float_as_int(p), 0x401F));
#endif

// ---- emission loads: round-13-PROVEN form (voff in VGPR, uniform s-base) ---
#define ISS1(REG, TT, COL) {                                                \
    int ts_ = (TT);                                                         \
    ts_ = ts_ < 0 ? 0 : (ts_ > (Tn - 1) ? (Tn - 1) : ts_);                  \
    const unsigned voff_ = (unsigned)ts_ * (unsigned)(Ln * 4) + (COL);      \
    asm volatile("global_load_dword %0, %1, %2"                             \
                 : "=v"(REG) : "v"(voff_), "s"(xb)); }

#define ISSUE16(P, TB)                                                      \
    ISS1(P##0,  (TB),            col4O) ISS1(P##1,  (TB) + 1  * dtt, col4E) \
    ISS1(P##2,  (TB) + 2 * dtt,  col4O) ISS1(P##3,  (TB) + 3  * dtt, col4E) \
    ISS1(P##4,  (TB) + 4 * dtt,  col4O) ISS1(P##5,  (TB) + 5  * dtt, col4E) \
    ISS1(P##6,  (TB) + 6 * dtt,  col4O) ISS1(P##7,  (TB) + 7  * dtt, col4E) \
    ISS1(P##8,  (TB) + 8 * dtt,  col4O) ISS1(P##9,  (TB) + 9  * dtt, col4E) \
    ISS1(P##10, (TB) + 10 * dtt, col4O) ISS1(P##11, (TB) + 11 * dtt, col4E) \
    ISS1(P##12, (TB) + 12 * dtt, col4O) ISS1(P##13, (TB) + 13 * dtt, col4E) \
    ISS1(P##14, (TB) + 14 * dtt, col4O) ISS1(P##15, (TB) + 15 * dtt, col4E)

#define WAITALL(P)                                                          \
    asm volatile("s_waitcnt vmcnt(0)"                                       \
        : "+v"(P##0), "+v"(P##1), "+v"(P##2),  "+v"(P##3),                  \
          "+v"(P##4), "+v"(P##5), "+v"(P##6),  "+v"(P##7),                  \
          "+v"(P##8), "+v"(P##9), "+v"(P##10), "+v"(P##11),                 \
          "+v"(P##12), "+v"(P##13), "+v"(P##14), "+v"(P##15)                \
        : : "memory");

#define COPY16(D, S)                                                        \
    D##0 = S##0;   D##1 = S##1;   D##2 = S##2;   D##3 = S##3;               \
    D##4 = S##4;   D##5 = S##5;   D##6 = S##6;   D##7 = S##7;               \
    D##8 = S##8;   D##9 = S##9;   D##10 = S##10; D##11 = S##11;             \
    D##12 = S##12; D##13 = S##13; D##14 = S##14; D##15 = S##15;

// ---- fused rotate-multiply: VOP2 DPP (one instruction per term) ------------
// DPP rotates src0 (xs). xs is produced inside an asm block with a glued
// s_nop 1 (2 wait states) so the gfx9 VALU-write -> DPP-read hazard cannot
// hit regardless of scheduling (hazard recognizer can't see into inline asm).
#define MULDPP(ACC, XS, EV, T)                                              \
    asm("v_mul_f32_dpp %0, %1, %2 row_ror:" #T " row_mask:0xf bank_mask:0xf"\
        : "=v"(ACC) : "v"(XS), "v"(EV));
#define FMACDPP(ACC, XS, EV, T)                                             \
    asm("v_fmac_f32_dpp %0, %1, %2 row_ror:" #T " row_mask:0xf bank_mask:0xf"\
        : "+v"(ACC) : "v"(XS), "v"(EV));

// ---- step core: alternating layout, ONE cross per step, DIR compile-time --
#define STEP_BODY(ET, CRX, PRE, NXTV)                                       \
    const float gcur = ggc;                                                 \
    if (PRE) ggc = __builtin_amdgcn_exp2f((NXTV) * LOG2E_F);                \
    float xs;                                                               \
    if constexpr (DIR) {                                                    \
        asm("v_mul_f32 %0, %1, %2\n\ts_nop 1"                               \
            : "=v"(xs) : "v"(x), "v"(gcur));                                \
    } else {                                                                \
        asm("v_mov_b32 %0, %1\n\ts_nop 1" : "=v"(xs) : "v"(x));             \
    }                                                                       \
    float a0, a1, a2, a3;                                                   \
    a0 = xs * ET[0];                                                        \
    MULDPP(a1, xs, ET[1], 1)                                                \
    MULDPP(a2, xs, ET[2], 2)                                                \
    MULDPP(a3, xs, ET[3], 3)                                                \
    FMACDPP(a0, xs, ET[4],  4)                                              \
    FMACDPP(a1, xs, ET[5],  5)                                              \
    FMACDPP(a2, xs, ET[6],  6)                                              \
    FMACDPP(a3, xs, ET[7],  7)                                              \
    FMACDPP(a0, xs, ET[8],  8)                                              \
    FMACDPP(a1, xs, ET[9],  9)                                              \
    FMACDPP(a2, xs, ET[10], 10)                                             \
    FMACDPP(a3, xs, ET[11], 11)                                             \
    FMACDPP(a0, xs, ET[12], 12)                                             \
    FMACDPP(a1, xs, ET[13], 13)                                             \
    FMACDPP(a2, xs, ET[14], 14)                                             \
    FMACDPP(a3, xs, ET[15], 15)                                             \
    const float partial = (a0 + a1) + (a2 + a3);                            \
    float cross; CRX(partial, cross)                                        \
    float full = partial + cross;                                           \
    if constexpr (!DIR) full *= gcur;      /* fw: emission at reader */

#define RENORM {                                                            \
    const int cb = __builtin_amdgcn_readfirstlane(                          \
        __float_as_int(fmaxf(capv, 1e-30f)));                               \
    const int ee = ((cb >> 23) & 255) - 127;                                \
    x *= __int_as_float((127 - ee) << 23);                                  \
    Mr += (float)ee; }

#define STEPF(ET, CRX, PRE, NXTV, CAP, RN) {                                \
    STEP_BODY(ET, CRX, PRE, NXTV)                                           \
    x = full;                                                               \
    if (CAP) capv = x;                                                      \
    if (RN) RENORM }

#define STEPT(R, ET, CRX, PRE, NXTV, CAP, RN) {                             \
    STEP_BODY(ET, CRX, PRE, NXTV)                                           \
    const bool act = ((kb + (R)) <= K);                                     \
    x = act ? full : x;                                                     \
    if (CAP) capv = x;                                                      \
    if (RN) RENORM }

#define STEPS16F(P)                                                         \
    ggc = __builtin_amdgcn_exp2f(P##0 * LOG2E_F);                           \
    STEPF(EiA, CROSS16, 1, P##1,  0, 0)                                     \
    STEPF(EiB, CROSS32, 1, P##2,  0, 0)                                     \
    STEPF(EiA, CROSS16, 1, P##3,  1, 0)                                     \
    STEPF(EiB, CROSS32, 1, P##4,  0, 1)                                     \
    STEPF(EiA, CROSS16, 1, P##5,  0, 0)                                     \
    STEPF(EiB, CROSS32, 1, P##6,  0, 0)                                     \
    STEPF(EiA, CROSS16, 1, P##7,  1, 0)                                     \
    STEPF(EiB, CROSS32, 1, P##8,  0, 1)                                     \
    STEPF(EiA, CROSS16, 1, P##9,  0, 0)                                     \
    STEPF(EiB, CROSS32, 1, P##10, 0, 0)                                     \
    STEPF(EiA, CROSS16, 1, P##11, 1, 0)                                     \
    STEPF(EiB, CROSS32, 1, P##12, 0, 1)                                     \
    STEPF(EiA, CROSS16, 1, P##13, 0, 0)                                     \
    STEPF(EiB, CROSS32, 1, P##14, 0, 0)                                     \
    STEPF(EiA, CROSS16, 1, P##15, 1, 0)                                     \
    STEPF(EiB, CROSS32, 0, P##15, 0, 1)                                     \
    kb += 16;

#define STEPS16T(P)                                                         \
    ggc = __builtin_amdgcn_exp2f(P##0 * LOG2E_F);                           \
    STEPT(0,  EiA, CROSS16, 1, P##1,  0, 0)                                 \
    STEPT(1,  EiB, CROSS32, 1, P##2,  0, 0)                                 \
    STEPT(2,  EiA, CROSS16, 1, P##3,  1, 0)                                 \
    STEPT(3,  EiB, CROSS32, 1, P##4,  0, 1)                                 \
    STEPT(4,  EiA, CROSS16, 1, P##5,  0, 0)                                 \
    STEPT(5,  EiB, CROSS32, 1, P##6,  0, 0)                                 \
    STEPT(6,  EiA, CROSS16, 1, P##7,  1, 0)                                 \
    STEPT(7,  EiB, CROSS32, 1, P##8,  0, 1)                                 \
    STEPT(8,  EiA, CROSS16, 1, P##9,  0, 0)                                 \
    STEPT(9,  EiB, CROSS32, 1, P##10, 0, 0)                                 \
    STEPT(10, EiA, CROSS16, 1, P##11, 1, 0)                                 \
    STEPT(11, EiB, CROSS32, 1, P##12, 0, 1)                                 \
    STEPT(12, EiA, CROSS16, 1, P##13, 0, 0)                                 \
    STEPT(13, EiB, CROSS32, 1, P##14, 0, 0)                                 \
    STEPT(14, EiA, CROSS16, 1, P##15, 1, 0)                                 \
    STEPT(15, EiB, CROSS32, 0, P##15, 0, 1)                                 \
    kb += 16;

#define EI_SETUP2                                                           \
    float EiA[16], EiB[16];                                                 \
    {                                                                       \
        float tmax = -3.4e38f;                                              \
        _Pragma("unroll")                                                   \
        for (int t = 0; t < 16; ++t) {                                      \
            const int sg = ror_minus ? ((k15 - t) & 15) : ((k15 + t) & 15); \
            const int iA = 16 * ihA + sg;                                   \
            const int iB = 16 * ihB + sg;                                   \
            const float tvA = DIR ? trans[labA * Ln + iA]                   \
                                  : trans[iA * Ln + labA];                  \
            const float tvB = DIR ? trans[labB * Ln + iB]                   \
                                  : trans[iB * Ln + labB];                  \
            EiA[t] = tvA;  EiB[t] = tvB;                                    \
            tmax = fmaxf(tmax, tvA);    /* EA spans all of trans */         \
        }                                                                   \
        _Pragma("unroll")                                                   \
        for (int off = 1; off < 64; off <<= 1)                              \
            tmax = fmaxf(tmax, __shfl_xor(tmax, off));                      \
        tmax2 = tmax * LOG2E_F;                                             \
        _Pragma("unroll")                                                   \
        for (int t = 0; t < 16; ++t) {                                      \
            EiA[t] = __builtin_amdgcn_exp2f((EiA[t] - tmax) * LOG2E_F);     \
            EiB[t] = __builtin_amdgcn_exp2f((EiB[t] - tmax) * LOG2E_F);     \
        }                                                                   \
    }

// ---- chain body, DIR compile-time ------------------------------------------
template<int DIR>
__device__ __forceinline__ void chain_run(const float* __restrict__ logits,
                                          const float* __restrict__ trans,
                                          const int b, const int l,
                                          const int len,
                                          float* __restrict__ ws)
{
    const int k15 = l & 15;
    const int labB = l & 31;                        // phi label
    const int labA = (l & 15) | ((l >> 5) << 4);    // sigma label
    const int ihA  = (l >> 4) & 1;                  // row-half, phi-layout
    const int ihB  = (l >> 5) & 1;                  // row-half, sigma-layout

    const int m  = (len + 1) >> 1;
    const int K  = DIR ? (len - m) : (m - 1);
    const int nfull = K >> 4;
    const int ktail = K & 15;

    const float* xb = logits + (size_t)b * (Tn * Ln);

    const int w0 = __builtin_amdgcn_readfirstlane(
        __builtin_amdgcn_update_dpp(0, l, 0x121, 0xF, 0xF, true));
    const bool ror_minus = (w0 == 15);
    PROBE32
    PROBE16

    float tmax2;
    EI_SETUP2

    // init state in phi-layout
    float x, Minit;
    if constexpr (DIR == 0) {
        const float a0v = xb[labB] * LOG2E_F;
        float mx = a0v;
        #pragma unroll
        for (int off = 1; off < 64; off <<= 1)
            mx = fmaxf(mx, __shfl_xor(mx, off));
        x = __builtin_amdgcn_exp2f(a0v - mx);
        Minit = mx;
    } else {
        x = 1.0f;
        Minit = 0.0f;
    }
    float Mr = 0.0f;
    float capv = x;

    const unsigned col4O = (unsigned)(DIR ? labB : labA) * 4u;
    const unsigned col4E = (unsigned)(DIR ? labA : labB) * 4u;
    const int dtt = DIR ? -1 : 1;
    const int t0  = DIR ? (len - 1) : 1;

    float A0, A1, A2, A3, A4, A5, A6, A7;
    float A8, A9, A10, A11, A12, A13, A14, A15;
    float B0, B1, B2, B3, B4, B5, B6, B7;
    float B8, B9, B10, B11, B12, B13, B14, B15;

    float ggc = 1.0f;
    int kb = 1;

    ISSUE16(B, t0)
    WAITALL(B)
    COPY16(A, B)
    int tnext = t0 + 16 * dtt;

    for (int g = 0; g < nfull; ++g) {
        ISSUE16(B, tnext)
        tnext += 16 * dtt;
        __builtin_amdgcn_sched_barrier(0);
        STEPS16F(A)
        __builtin_amdgcn_sched_barrier(0);
        WAITALL(B)
        __builtin_amdgcn_sched_barrier(0);
        COPY16(A, B)
    }
    if (ktail) {
        STEPS16T(A)
    }

    asm volatile("s_waitcnt vmcnt(0)" ::: "memory");

    const float M = Minit + (float)K * tmax2 + Mr;

    // final layout depends on parity of K: even -> phi, odd -> sigma
    float* wsrow = ws + (size_t)(b * 2 + DIR) * 33;
    if (K & 1) {
        if ((l & 16) == 0) wsrow[labA] = x;
    } else {
        if (l < 32) wsrow[l] = x;
    }
    if (l == 0) wsrow[32] = M;
}

__global__ __launch_bounds__(64)
void crf_chain_kernel(const float* __restrict__ logits,
                      const float* __restrict__ trans,
                      const int* __restrict__ seq_lens,
                      float* __restrict__ ws)
{
    const int blk = blockIdx.x;
    const int b   = blk >> 1;
    const int dir = blk & 1;
    const int l   = threadIdx.x;

    int len = seq_lens[b];
    len = len < 1 ? 1 : (len > Tn ? Tn : len);
    len = __builtin_amdgcn_readfirstlane(len);   // uniform: scalar t-arithmetic

    if (dir == 0) chain_run<0>(logits, trans, b, l, len, ws);
    else          chain_run<1>(logits, trans, b, l, len, ws);
}

// ---- combine kernel: 256 threads (gather latency spread over 4 waves) ------
__global__ __launch_bounds__(256)
void crf_combine_kernel(const float* __restrict__ logits,
                        const float* __restrict__ trans,
                        const int* __restrict__ labels,
                        const int* __restrict__ seq_lens,
                        const float* __restrict__ ws,
                        float* __restrict__ out)
{
    const int b   = blockIdx.x;
    const int tid = threadIdx.x;

    int len = seq_lens[b];
    len = len < 1 ? 1 : (len > Tn ? Tn : len);

    const int*   lb = labels + (size_t)b * Tn;
    const float* xb = logits + (size_t)b * (Tn * Ln);

    float acc = 0.f;
    for (int t = tid; t < len; t += 256) {
        const int lt = lb[t];
        acc += xb[t * Ln + lt];
        if (t >= 1) acc += trans[lb[t - 1] * Ln + lt];
    }
    #pragma unroll
    for (int off = 1; off < 64; off <<= 1)
        acc += __shfl_xor(acc, off);

    __shared__ float wred[4];
    if ((tid & 63) == 0) wred[tid >> 6] = acc;
    __syncthreads();

    if (tid < 64) {
        const float gold = (wred[0] + wred[1]) + (wred[2] + wred[3]);
        const int j = tid & 31;
        const float* wf = ws + (size_t)(b * 2 + 0) * 33;
        const float* wb = ws + (size_t)(b * 2 + 1) * 33;
        float term = wf[j] * wb[j];
        #pragma unroll
        for (int off = 1; off < 32; off <<= 1)
            term += __shfl_xor(term, off);
        if (tid == 0) {
            const float Mf = wf[32], Mb = wb[32];
            out[b] = gold - (Mf + Mb + __builtin_amdgcn_logf(term)) * LN2_F;
        }
    }
}

extern "C" void kernel_launch(void* const* d_in, const int* in_sizes, int n_in,
                              void* d_out, int out_size, void* d_ws, size_t ws_size,
                              hipStream_t stream) {
    const float* logits   = (const float*)d_in[0];
    const float* trans    = (const float*)d_in[1];
    const int*   labels   = (const int*)d_in[2];
    const int*   seq_lens = (const int*)d_in[3];
    float* out = (float*)d_out;
    float* ws  = (float*)d_ws;    // 2048 * 33 floats = 270 KB

    crf_chain_kernel<<<Bn * 2, 64, 0, stream>>>(logits, trans, seq_lens, ws);
    crf_combine_kernel<<<Bn, 256, 0, stream>>>(logits, trans, labels, seq_lens, ws, out);
}